// Round 10
// baseline (471.084 us; speedup 1.0000x reference)
//
#include <hip/hip_runtime.h>

typedef unsigned char u8;
typedef unsigned long long u64;
typedef _Float16 h2 __attribute__((ext_vector_type(2)));

__device__ inline h2 h2bits(unsigned int u) { union { unsigned int u; h2 h; } c; c.u = u; return c.h; }
__device__ inline unsigned int bitsh2(h2 h) { union { unsigned int u; h2 h; } c; c.h = h; return c.u; }
__device__ inline unsigned int f2hbits(float v) {
    union { _Float16 h; unsigned short u; } c; c.h = (_Float16)v; return (unsigned int)c.u;
}

#if __has_builtin(__builtin_amdgcn_fdot2)
__device__ inline float fdot2(h2 a, h2 b, float c) { return __builtin_amdgcn_fdot2(a, b, c, false); }
#else
__device__ inline float fdot2(h2 a, h2 b, float c) {
    return c + (float)a.x * (float)b.x + (float)a.y * (float)b.y;
}
#endif

// ---------------- K0t: codebook norms, zero loss, weight re-layouts ----------------
__global__ __launch_bounds__(256) void k0t(const float* __restrict__ cb,
                                           float* __restrict__ cnorm,
                                           float* __restrict__ lossacc,
                                           const float* __restrict__ e2w,
                                           float* __restrict__ wT2,
                                           const float* __restrict__ d1w,
                                           unsigned int* __restrict__ wH6u,
                                           const float* __restrict__ d2w,
                                           unsigned int* __restrict__ wH7u) {
    int g = blockIdx.x * 256 + threadIdx.x;   // 8192 threads
    if (g < 1024) {
        float s = 0.f;
#pragma unroll
        for (int d = 0; d < 25; ++d) { float v = cb[g * 25 + d]; s += v * v; }
        cnorm[g] = s;
    }
    if (g == 0) lossacc[0] = 0.f;   // ws poisoned 0xAA each call
    for (int i = g; i < 27648; i += 8192) {
        int oc = i / 288, r = i % 288, ci = r / 9, k = r % 9;
        wT2[((ci * 3 + k / 3) * 96 + oc) * 3 + (k % 3)] = e2w[i];
    }
    for (int i = g; i < 13824; i += 8192) {
        int oc = i & 31, r = i >> 5;            // r = (cp*3+ky)*3+kx
        int kx = r % 3, r2 = r / 3, ky = r2 % 3, cp = r2 / 3;
        float a = d1w[(oc * 96 + 2 * cp) * 9 + ky * 3 + kx];
        float b = d1w[(oc * 96 + 2 * cp + 1) * 9 + ky * 3 + kx];
        h2 v; v.x = (_Float16)a; v.y = (_Float16)b;
        wH6u[i] = bitsh2(v);
    }
    if (g < 432) {
        int oc = g % 3, r = g / 3;
        int kx = r % 3, r2 = r / 3, ky = r2 % 3, cp = r2 / 3;
        float a = d2w[(oc * 32 + 2 * cp) * 9 + ky * 3 + kx];
        float b = d2w[(oc * 32 + 2 * cp + 1) * 9 + ky * 3 + kx];
        h2 v; v.x = (_Float16)a; v.y = (_Float16)b;
        wH7u[g] = bitsh2(v);
    }
}

// ---------------- K1: enc1 conv3x3(3->32)+relu+pool, lane = pooled pos ----------------
__global__ __launch_bounds__(128) void k1_enc1(const float* __restrict__ x,
                                               const float* __restrict__ w,   // [32][3][9]
                                               const float* __restrict__ bias,
                                               float* __restrict__ p1,
                                               u64* __restrict__ idx1p) {
    const int img = blockIdx.x;
    const int tid = threadIdx.x;
    __shared__ __align__(16) float xs[1320];   // [3][20][22], x-padded
    __shared__ float wss[864];
    __shared__ float bss[32];
    for (int i = tid; i < 1320; i += 128) xs[i] = 0.f;
    for (int i = tid; i < 864; i += 128) wss[i] = w[i];
    if (tid < 32) bss[tid] = bias[tid];
    __syncthreads();
    for (int i = tid; i < 1200; i += 128) {
        int ci = i / 400, s = i % 400, y = s / 20, xx = s % 20;
        xs[ci * 440 + y * 22 + xx + 1] = x[img * 1200 + i];
    }
    __syncthreads();
    if (tid >= 100) return;   // only LDS reads below; no barriers
    const int r = tid / 10, c = tid % 10;
    int ry[4]; bool mv[4];
#pragma unroll
    for (int wy = 0; wy < 4; ++wy) {
        int yy = 2 * r - 1 + wy;
        mv[wy] = (yy >= 0) && (yy <= 19);
        ry[wy] = min(max(yy, 0), 19);
    }
    u64 idxbits = 0;
    for (int ocg = 0; ocg < 4; ++ocg) {
        float acc[8][4];
#pragma unroll
        for (int j = 0; j < 8; ++j) {
            float bb = bss[ocg * 8 + j];
#pragma unroll
            for (int q = 0; q < 4; ++q) acc[j][q] = bb;
        }
        for (int ci = 0; ci < 3; ++ci) {
            float win[4][4];
#pragma unroll
            for (int wy = 0; wy < 4; ++wy)
#pragma unroll
                for (int wx = 0; wx < 4; ++wx) {
                    float v = xs[ci * 440 + ry[wy] * 22 + 2 * c + wx];
                    win[wy][wx] = mv[wy] ? v : 0.f;
                }
#pragma unroll
            for (int j = 0; j < 8; ++j) {
                const float* wr = &wss[((ocg * 8 + j) * 3 + ci) * 9];
#pragma unroll
                for (int q = 0; q < 4; ++q) {
                    int dr = q >> 1, dc = q & 1;
#pragma unroll
                    for (int ky = 0; ky < 3; ++ky)
#pragma unroll
                        for (int kx = 0; kx < 3; ++kx)
                            acc[j][q] = fmaf(win[dr + ky][dc + kx], wr[ky * 3 + kx], acc[j][q]);
                }
            }
        }
#pragma unroll
        for (int j = 0; j < 8; ++j) {
            int oc = ocg * 8 + j;
            float best = -1.f; int bi = 0;
#pragma unroll
            for (int q = 0; q < 4; ++q) {            // relu then FIRST-max
                float v = fmaxf(acc[j][q], 0.f);
                if (v > best) { best = v; bi = q; }
            }
            p1[img * 3200 + oc * 100 + tid] = best;
            idxbits |= (u64)bi << (2 * oc);
        }
    }
    idx1p[img * 100 + tid] = idxbits;
}

// ---------------- K2f (R7 shape): enc2 conv+relu+pool fused with pre-VQ 1x1 ----------
// 256 thr; wave=24oc (12 per lane-half), lane=2x2 pooled quad; 8-ci weight chunks.
__global__ __launch_bounds__(256) void k2f(const float* __restrict__ p1,
                                           const float* __restrict__ wT2,  // [ci][ky][96][3]
                                           const float* __restrict__ bias,
                                           const float* __restrict__ prw,  // [128][96]
                                           const float* __restrict__ prb,
                                           float* __restrict__ vqb,
                                           u8* __restrict__ idx2) {
    const int img = blockIdx.x;
    const int tid = threadIdx.x;
    __shared__ __align__(16) float up[4608];    // [32][12][12] y&x padded; phase2: ob
    __shared__ __align__(16) float wch[6912];   // 8 ci x [3ky][96oc*3kx]; phase2: zs+wst
    for (int i = tid; i < 4608; i += 256) up[i] = 0.f;
    __syncthreads();
    for (int i = tid; i < 3200; i += 256) {
        int ci = i / 100, s = i % 100;
        up[ci * 144 + (s / 10 + 1) * 12 + (s % 10) + 1] = p1[img * 3200 + i];
    }
    const int wv = tid >> 6;             // wave 0..3 (wave-uniform)
    const int l  = tid & 63;
    const int ocsub = (l >= 25) ? 1 : 0; // 2 distinct weight addrs per wave -> free
    const int pos = l - ocsub * 25;      // 0..24 pooled pos
    const bool act = (l < 50);
    const int oc0 = wv * 24 + ocsub * 12;
    const int r = pos / 5, c = pos % 5;
    float acc[12][4];
#pragma unroll
    for (int j = 0; j < 12; ++j)
#pragma unroll
        for (int q = 0; q < 4; ++q) acc[j][q] = 0.f;
    for (int chunk = 0; chunk < 4; ++chunk) {
        __syncthreads();
        for (int i = tid; i < 6912; i += 256) wch[i] = wT2[chunk * 6912 + i];
        __syncthreads();
        if (act) {
            for (int cil = 0; cil < 8; ++cil) {
                const int base = (chunk * 8 + cil) * 144;
                float win[4][4];
#pragma unroll
                for (int wy = 0; wy < 4; ++wy) {
                    float2 a = *(const float2*)&up[base + (2 * r + wy) * 12 + 2 * c];
                    float2 b = *(const float2*)&up[base + (2 * r + wy) * 12 + 2 * c + 2];
                    win[wy][0] = a.x; win[wy][1] = a.y; win[wy][2] = b.x; win[wy][3] = b.y;
                }
#pragma unroll
                for (int ky = 0; ky < 3; ++ky) {
                    const float* wk = &wch[(cil * 3 + ky) * 288 + oc0 * 3];
                    float wreg[36];
#pragma unroll
                    for (int i4 = 0; i4 < 9; ++i4)
                        *(float4*)(wreg + 4 * i4) = *(const float4*)(wk + 4 * i4);
#pragma unroll
                    for (int j = 0; j < 12; ++j)
#pragma unroll
                        for (int q = 0; q < 4; ++q) {
                            int dr = q >> 1, dc = q & 1;
#pragma unroll
                            for (int kx = 0; kx < 3; ++kx)
                                acc[j][q] = fmaf(win[dr + ky][dc + kx], wreg[j * 3 + kx], acc[j][q]);
                        }
                }
            }
        }
    }
    // ---- pool, write idx2 + z into LDS (zs overlays wch; barrier first) ----
    float* zs = wch;              // [96][28] = 2688
    float* wst = &wch[2688];      // 128 x pad33 = 4224 (2688+4224 = 6912)
    __syncthreads();              // all waves done reading wch/up
    if (act) {
#pragma unroll
        for (int j = 0; j < 12; ++j) {
            int oc = oc0 + j;
            float bb = bias[oc];
            float best = -1.f; int bi = 0;
#pragma unroll
            for (int q = 0; q < 4; ++q) {            // relu BEFORE pool; FIRST max
                float v = fmaxf(acc[j][q] + bb, 0.f);
                if (v > best) { best = v; bi = q; }
            }
            zs[oc * 28 + pos] = best;
            idx2[img * 2400 + oc * 25 + pos] = (u8)bi;
        }
    }
    __syncthreads();
    // ---- phase 2: vq = prw @ z + prb (bias, then ci ascending) ----
    const int e = tid >> 1, sh = tid & 1;
    const int s0 = sh * 12, ns = sh ? 13 : 12;
    float acc2[13];
    {
        float bb = prb[e];
#pragma unroll
        for (int k = 0; k < 13; ++k) acc2[k] = bb;
    }
    for (int cc = 0; cc < 3; ++cc) {
        __syncthreads();
        for (int i = tid; i < 4096; i += 256)
            wst[(i >> 5) * 33 + (i & 31)] = prw[(i >> 5) * 96 + cc * 32 + (i & 31)];
        __syncthreads();
        for (int cil = 0; cil < 32; ++cil) {
            int ci = cc * 32 + cil;
            float wvv = wst[e * 33 + cil];         // bank (e+cil)%32 -> conflict-free
            float cz[16];
#pragma unroll
            for (int i4 = 0; i4 < 4; ++i4)
                *(float4*)(cz + 4 * i4) = *(const float4*)&zs[ci * 28 + s0 + 4 * i4];
#pragma unroll
            for (int k = 0; k < 13; ++k) acc2[k] = fmaf(wvv, cz[k], acc2[k]);
        }
    }
    float* ob = up;   // up dead after phase 1
#pragma unroll
    for (int k = 0; k < 13; ++k)
        if (k < ns) ob[e * 25 + s0 + k] = acc2[k];
    __syncthreads();
    for (int i = tid; i < 3200; i += 256) vqb[img * 3200 + i] = ob[i];
}

// ---------------- K3b: VQ distances, code-chunked, broadcast LDS reads ----------------
__global__ __launch_bounds__(256) void k3b_vq2(const float* __restrict__ vq,
                                               const float* __restrict__ cb,
                                               const float* __restrict__ cnorm,
                                               float* __restrict__ pbest,
                                               int* __restrict__ pbk) {
    const int tg = blockIdx.x >> 3;      // 0..127
    const int ch = blockIdx.x & 7;       // 0..7
    const int tid = threadIdx.x;
    const int k0 = ch * 128;
    __shared__ __align__(16) float cs[128 * 28];
    for (int i = tid; i < 128 * 28; i += 256) {
        int k = i / 28, d = i % 28;
        float v = 0.f;
        if (d < 25) v = cb[(k0 + k) * 25 + d];
        else if (d == 25) v = cnorm[k0 + k];
        cs[i] = v;
    }
    const int t0 = tg * 1024 + tid * 4;
    float f2[4][25];
#pragma unroll
    for (int t = 0; t < 4; ++t)
#pragma unroll
        for (int d = 0; d < 25; ++d)
            f2[t][d] = -2.f * vq[(t0 + t) * 25 + d];
    __syncthreads();
    float best[4] = {1e30f, 1e30f, 1e30f, 1e30f};
    int bk[4] = {0, 0, 0, 0};
    for (int k = 0; k < 128; ++k) {
        const float* crow = &cs[k * 28];
        float cc[28];
#pragma unroll
        for (int i = 0; i < 7; ++i)
            *(float4*)(cc + 4 * i) = *(const float4*)(crow + 4 * i);
        const float cn = cc[25];
        const int kg = k0 + k;
#pragma unroll
        for (int t = 0; t < 4; ++t) {
            float a = cn;
#pragma unroll
            for (int d = 0; d < 25; ++d) a = fmaf(f2[t][d], cc[d], a);
            if (a < best[t]) { best[t] = a; bk[t] = kg; }   // first-min
        }
    }
#pragma unroll
    for (int t = 0; t < 4; ++t) {
        pbest[ch * 131072 + t0 + t] = best[t];
        pbk[ch * 131072 + t0 + t] = bk[t];
    }
}

// ---------------- K3r: merge chunk partials, indices, loss ----------------
__global__ __launch_bounds__(256) void k3r_reduce(const float* __restrict__ pbest,
                                                  const int* __restrict__ pbk,
                                                  const float* __restrict__ vq,
                                                  int* __restrict__ vqidx,
                                                  float* __restrict__ lossacc) {
    const int t = blockIdx.x * 256 + threadIdx.x;
    float best = 1e30f; int bk = 0;
#pragma unroll
    for (int ch = 0; ch < 8; ++ch) {
        float s = pbest[ch * 131072 + t];
        int k = pbk[ch * 131072 + t];
        if (s < best) { best = s; bk = k; }
    }
    vqidx[t] = bk;
    float fn = 0.f;
#pragma unroll
    for (int d = 0; d < 25; ++d) { float v = vq[t * 25 + d]; fn = fmaf(v, v, fn); }
    float dloc = fn + best;
#pragma unroll
    for (int off = 32; off > 0; off >>= 1) dloc += __shfl_down(dloc, off, 64);
    __shared__ float wsum[4];
    if ((threadIdx.x & 63) == 0) wsum[threadIdx.x >> 6] = dloc;
    __syncthreads();
    if (threadIdx.x == 0)
        atomicAdd(lossacc, wsum[0] + wsum[1] + wsum[2] + wsum[3]);
}

__global__ void kf_loss(const float* __restrict__ lossacc, float* __restrict__ out) {
    out[0] = 0.25f * lossacc[0] / 3276800.0f;
}

// ---------------- K5 v2: gather codebook, trans 1x1 (128->96) + pose head ----------------
// Trans conv: 4 waves; wave -> 24 oc (12 per lane-half), lane = spatial pos (0..24).
// tw staged per-32-e chunk in LDS -> wave-broadcast b128 reads; e ascending, bias at end
// (same summation order as previous k5).
__global__ __launch_bounds__(256) void k5_latent_pose(
    const int* __restrict__ vqidx, const float* __restrict__ cb,
    const float* __restrict__ tw, const float* __restrict__ tbb,
    const float* __restrict__ w1, const float* __restrict__ b1,
    const float* __restrict__ w2, const float* __restrict__ b2,
    float* __restrict__ latg, float* __restrict__ outkp) {
    const int img = blockIdx.x;
    const int tid = threadIdx.x;
    __shared__ int idxs[128];
    __shared__ __align__(16) float zr[128 * 26];   // [e][pos] pad26
    __shared__ float lat[2400];                    // [96][25]
    __shared__ __align__(16) float tws[3072];      // 32 e x 96 oc
    __shared__ float ps[256];
    __shared__ float hs[32];
    if (tid < 128) idxs[tid] = vqidx[img * 128 + tid];
    __syncthreads();
    for (int i = tid; i < 3200; i += 256) {
        int e = i / 25, d = i % 25;
        zr[e * 26 + d] = cb[idxs[e] * 25 + d];
    }
    const int wv = tid >> 6;             // wave 0..3 (wave-uniform)
    const int l  = tid & 63;
    const int ocsub = (l >= 25) ? 1 : 0; // 2 distinct weight addrs per wave -> free
    const int pos = l - ocsub * 25;
    const bool act = (l < 50);
    const int oc0 = wv * 24 + ocsub * 12;
    float acc[12];
#pragma unroll
    for (int j = 0; j < 12; ++j) acc[j] = 0.f;
    for (int ch = 0; ch < 4; ++ch) {
        __syncthreads();                 // also covers zr-write completion on ch==0
        for (int i = tid; i < 3072; i += 256)
            tws[i] = tw[ch * 32 * 96 + i];
        __syncthreads();
        if (act) {
            for (int el = 0; el < 32; ++el) {
                float zv = zr[(ch * 32 + el) * 26 + pos];   // stride-1 across lanes
                const float* twr = &tws[el * 96 + oc0];     // wave: 2 distinct addrs
                float wreg[12];
#pragma unroll
                for (int i4 = 0; i4 < 3; ++i4)
                    *(float4*)(wreg + 4 * i4) = *(const float4*)(twr + 4 * i4);
#pragma unroll
                for (int j = 0; j < 12; ++j) acc[j] = fmaf(zv, wreg[j], acc[j]);
            }
        }
    }
    if (act) {
#pragma unroll
        for (int j = 0; j < 12; ++j) {
            float v = acc[j] + tbb[oc0 + j];
            lat[(oc0 + j) * 25 + pos] = v;
            latg[img * 2400 + (oc0 + j) * 25 + pos] = v;
        }
    }
    __syncthreads();
    {
        const int seg = tid >> 5, jj = tid & 31;
        float s = 0.f;
        const int i0 = seg * 300;
        for (int i = i0; i < i0 + 300; ++i) s += lat[i] * w1[i * 32 + jj];
        ps[seg * 32 + jj] = s;
    }
    __syncthreads();
    if (tid < 32) {
        float h = b1[tid];
#pragma unroll
        for (int s2 = 0; s2 < 8; ++s2) h += ps[s2 * 32 + tid];
        hs[tid] = fmaxf(h, 0.f);
    }
    __syncthreads();
    if (tid < 36) {
        float kp = b2[tid];
#pragma unroll
        for (int m = 0; m < 32; ++m) kp += hs[m] * w2[m * 36 + tid];
        outkp[img * 36 + tid] = kp;
    }
}

// ---------------- K6 v5: unpool(idx2)+dec1 f16 dot2; 4 images/block, cp-halved ----------
__global__ __launch_bounds__(256) void k6_dec1(const float* __restrict__ latg,
                                               const u8* __restrict__ idx2,
                                               const unsigned int* __restrict__ wH6,
                                               const float* __restrict__ bias,
                                               unsigned short* __restrict__ d1h) {
    const int img0 = blockIdx.x * 4;
    const int tid = threadIdx.x;
    __shared__ __align__(16) unsigned int uph[13824];  // 4 img x [24cp][12][12] half2
    __shared__ unsigned int wcs[2304];                 // 8cp x [9 tap][32 oc] half2
    const int m = tid >> 6;          // wave = image (wave-uniform)
    const int l = tid & 63;
    const int oc = l & 31, ys = l >> 5;
    float acc[50];
#pragma unroll
    for (int i = 0; i < 50; ++i) acc[i] = 0.f;
    for (int half = 0; half < 2; ++half) {
        __syncthreads();             // prior compute done before re-zero
        for (int i = tid; i < 13824; i += 256) uph[i] = 0u;
        __syncthreads();
        // quad-owner staging (full-word writes, race-free): 4 img x 24 cp x 25 pos
        for (int g = tid; g < 2400; g += 256) {
            int mi = g / 600, r2 = g % 600;
            int cpl = r2 / 25, s = r2 % 25;
            int cp = half * 24 + cpl;
            int rr = (img0 + mi) * 2400 + cp * 50 + s;
            int q0 = idx2[rr], q1 = idx2[rr + 25];
            float v0 = latg[rr], v1 = latg[rr + 25];
            unsigned int wq[4] = {0u, 0u, 0u, 0u};
            wq[q0] |= f2hbits(v0);
            wq[q1] |= f2hbits(v1) << 16;
            int pr = s / 5, pc = s % 5;
            int wb = mi * 3456 + (cpl * 12 + 2 * pr + 1) * 12 + 2 * pc + 1;
            uph[wb]      = wq[0];
            uph[wb + 1]  = wq[1];
            uph[wb + 12] = wq[2];
            uph[wb + 13] = wq[3];
        }
        for (int chunk = 0; chunk < 3; ++chunk) {
            __syncthreads();
            for (int i = tid; i < 2304; i += 256) wcs[i] = wH6[(half * 3 + chunk) * 2304 + i];
            __syncthreads();
            for (int cpl = 0; cpl < 8; ++cpl) {
                const int base = m * 3456 + (chunk * 8 + cpl) * 144 + ys * 60;
                unsigned int row[7][12];
#pragma unroll
                for (int k = 0; k < 7; ++k) {
                    const uint4* rp = (const uint4*)&uph[base + k * 12];
                    uint4 a = rp[0], b = rp[1], cc = rp[2];
                    row[k][0] = a.x;  row[k][1] = a.y;  row[k][2] = a.z;  row[k][3] = a.w;
                    row[k][4] = b.x;  row[k][5] = b.y;  row[k][6] = b.z;  row[k][7] = b.w;
                    row[k][8] = cc.x; row[k][9] = cc.y; row[k][10] = cc.z; row[k][11] = cc.w;
                }
                h2 w9[9];
#pragma unroll
                for (int t = 0; t < 9; ++t) w9[t] = h2bits(wcs[(cpl * 9 + t) * 32 + oc]);
#pragma unroll
                for (int r = 0; r < 5; ++r)
#pragma unroll
                    for (int j = 0; j < 10; ++j) {
                        float a = acc[r * 10 + j];
#pragma unroll
                        for (int ky = 0; ky < 3; ++ky)
#pragma unroll
                            for (int kx = 0; kx < 3; ++kx)
                                a = fdot2(h2bits(row[r + ky][j + kx]), w9[ky * 3 + kx], a);
                        acc[r * 10 + j] = a;
                    }
            }
        }
    }
    const float bb = bias[oc];
#pragma unroll
    for (int r = 0; r < 5; ++r)
#pragma unroll
        for (int j = 0; j < 10; ++j)
            d1h[(img0 + m) * 3200 + ((ys * 5 + r) * 10 + j) * 32 + oc] =
                (unsigned short)f2hbits(fmaxf(acc[r * 10 + j] + bb, 0.f));
}

// ---------------- K7 v2: unpool(idx1) + dec2 via f16 dot2 -> r_x ----------------
__global__ __launch_bounds__(256) void k7_dec2(const unsigned int* __restrict__ d1w32,
                                               const u64* __restrict__ idx1p,
                                               const unsigned int* __restrict__ wH7,
                                               const float* __restrict__ bias,
                                               float* __restrict__ rx) {
    const int img = blockIdx.x;
    const int tid = threadIdx.x;
    __shared__ __align__(16) unsigned int uph[7040];   // [16cp][20][22] half2, x-padded
    __shared__ unsigned int wcs[448];                  // cp*28 + tap*3 + oc (27 used)
    for (int i = tid; i < 7040; i += 256) uph[i] = 0u;
    for (int i = tid; i < 448; i += 256) {
        int cp = i / 28, rr = i % 28;
        wcs[i] = (rr < 27) ? wH7[cp * 27 + rr] : 0u;
    }
    __syncthreads();
    for (int g = tid; g < 1600; g += 256) {
        int pos = g >> 4, cp = g & 15;
        unsigned int word = d1w32[img * 1600 + g];
        u64 bits = idx1p[img * 100 + pos];
        int q0 = (int)((bits >> (4 * cp)) & 3ull);
        int q1 = (int)((bits >> (4 * cp + 2)) & 3ull);
        unsigned int wq[4] = {0u, 0u, 0u, 0u};
        wq[q0] |= word & 0xFFFFu;
        wq[q1] |= word & 0xFFFF0000u;
        int r = pos / 10, c = pos % 10;
        int wb = cp * 440 + (2 * r) * 22 + 2 * c + 1;
        uph[wb]      = wq[0];
        uph[wb + 1]  = wq[1];
        uph[wb + 22] = wq[2];
        uph[wb + 23] = wq[3];
    }
    __syncthreads();
    if (tid >= 200) return;   // only LDS reads below
    const int y = tid / 10, xp = tid % 10, x0 = 2 * xp;
    const bool m0 = (y > 0), m2 = (y < 19);
    const int ry0 = max(y - 1, 0), ry2 = min(y + 1, 19);
    float acc[3][2] = {{0.f, 0.f}, {0.f, 0.f}, {0.f, 0.f}};
    for (int cp = 0; cp < 16; ++cp) {
        const int base = cp * 440;
        unsigned int row[3][4];
        {
            uint2 a = *(const uint2*)&uph[base + ry0 * 22 + x0];
            uint2 b = *(const uint2*)&uph[base + ry0 * 22 + x0 + 2];
            row[0][0] = m0 ? a.x : 0u; row[0][1] = m0 ? a.y : 0u;
            row[0][2] = m0 ? b.x : 0u; row[0][3] = m0 ? b.y : 0u;
            a = *(const uint2*)&uph[base + y * 22 + x0];
            b = *(const uint2*)&uph[base + y * 22 + x0 + 2];
            row[1][0] = a.x; row[1][1] = a.y; row[1][2] = b.x; row[1][3] = b.y;
            a = *(const uint2*)&uph[base + ry2 * 22 + x0];
            b = *(const uint2*)&uph[base + ry2 * 22 + x0 + 2];
            row[2][0] = m2 ? a.x : 0u; row[2][1] = m2 ? a.y : 0u;
            row[2][2] = m2 ? b.x : 0u; row[2][3] = m2 ? b.y : 0u;
        }
#pragma unroll
        for (int oc = 0; oc < 3; ++oc)
#pragma unroll
            for (int ky = 0; ky < 3; ++ky)
#pragma unroll
                for (int kx = 0; kx < 3; ++kx) {
                    h2 wk = h2bits(wcs[cp * 28 + (ky * 3 + kx) * 3 + oc]);
                    acc[oc][0] = fdot2(h2bits(row[ky][kx]),     wk, acc[oc][0]);
                    acc[oc][1] = fdot2(h2bits(row[ky][kx + 1]), wk, acc[oc][1]);
                }
    }
#pragma unroll
    for (int oc = 0; oc < 3; ++oc)
#pragma unroll
        for (int dx = 0; dx < 2; ++dx)
            rx[img * 1200 + oc * 400 + y * 20 + x0 + dx] = acc[oc][dx] + bias[oc];
}

extern "C" void kernel_launch(void* const* d_in, const int* in_sizes, int n_in,
                              void* d_out, int out_size, void* d_ws, size_t ws_size,
                              hipStream_t stream) {
    const float* x   = (const float*)d_in[0];
    const float* e1w = (const float*)d_in[1];
    const float* e1b = (const float*)d_in[2];
    const float* e2w = (const float*)d_in[3];
    const float* e2b = (const float*)d_in[4];
    const float* prw = (const float*)d_in[5];
    const float* prb = (const float*)d_in[6];
    const float* cb  = (const float*)d_in[7];
    const float* tw  = (const float*)d_in[8];
    const float* tbb = (const float*)d_in[9];
    const float* d1w = (const float*)d_in[10];
    const float* d1b = (const float*)d_in[11];
    const float* d2w = (const float*)d_in[12];
    const float* d2b = (const float*)d_in[13];
    const float* hw1 = (const float*)d_in[14];
    const float* hb1 = (const float*)d_in[15];
    const float* hw2 = (const float*)d_in[16];
    const float* hb2 = (const float*)d_in[17];
    float* out = (float*)d_out;

    float* ws      = (float*)d_ws;
    float* cnorm   = ws;                         // 1024
    float* lossacc = cnorm + 1024;               // 4
    float* wT2     = lossacc + 4;                // 27648
    unsigned int* wH6u = (unsigned int*)(wT2 + 27648);   // 13824 u32
    unsigned int* wH7u = wH6u + 13824;                   // 432 u32
    float* p1      = wT2 + 27648 + 27648;        // 3,276,800 (reused as latent after k2f)
    float* z       = p1 + 3276800;               // 2,457,600 (pbest/pbk overlay)
    float* vq      = z + 2457600;                // 3,276,800 (reused as d1h after k3r)
    int*   vqidx   = (int*)(vq + 3276800);       // 131,072
    u64*   idx1p   = (u64*)(vqidx + 131072);     // 102,400 u64
    u8*    idx2    = (u8*)(idx1p + 102400);      // 2,457,600 B
    float* latent  = p1;
    unsigned short* d1h = (unsigned short*)vq;   // 1024 x 3200 f16
    float* pbest   = z;                          // 1,048,576
    int*   pbk     = (int*)(z + 1048576);        // 1,048,576

    float* rx  = out + 1;
    float* okp = out + 1 + 1228800;

    k0t<<<32, 256, 0, stream>>>(cb, cnorm, lossacc, e2w, wT2, d1w, wH6u, d2w, wH7u);
    k1_enc1<<<1024, 128, 0, stream>>>(x, e1w, e1b, p1, idx1p);
    k2f<<<1024, 256, 0, stream>>>(p1, wT2, e2b, prw, prb, vq, idx2);
    k3b_vq2<<<1024, 256, 0, stream>>>(vq, cb, cnorm, pbest, pbk);
    k3r_reduce<<<512, 256, 0, stream>>>(pbest, pbk, vq, vqidx, lossacc);
    kf_loss<<<1, 1, 0, stream>>>(lossacc, out);
    k5_latent_pose<<<1024, 256, 0, stream>>>(vqidx, cb, tw, tbb, hw1, hb1, hw2, hb2,
                                             latent, okp);
    k6_dec1<<<256, 256, 0, stream>>>(latent, idx2, wH6u, d1b, d1h);
    k7_dec2<<<1024, 256, 0, stream>>>((const unsigned int*)d1h, idx1p, wH7u, d2b, rx);
}

// Round 11
// 439.095 us; speedup vs baseline: 1.0729x; 1.0729x over previous
//
#include <hip/hip_runtime.h>

typedef unsigned char u8;
typedef unsigned long long u64;
typedef _Float16 h2 __attribute__((ext_vector_type(2)));

__device__ inline h2 h2bits(unsigned int u) { union { unsigned int u; h2 h; } c; c.u = u; return c.h; }
__device__ inline unsigned int bitsh2(h2 h) { union { unsigned int u; h2 h; } c; c.h = h; return c.u; }
__device__ inline unsigned int f2hbits(float v) {
    union { _Float16 h; unsigned short u; } c; c.h = (_Float16)v; return (unsigned int)c.u;
}

#if __has_builtin(__builtin_amdgcn_fdot2)
__device__ inline float fdot2(h2 a, h2 b, float c) { return __builtin_amdgcn_fdot2(a, b, c, false); }
#else
__device__ inline float fdot2(h2 a, h2 b, float c) {
    return c + (float)a.x * (float)b.x + (float)a.y * (float)b.y;
}
#endif

// ---------------- K0t: codebook norms, zero loss, weight re-layouts ----------------
// wT2:  e2w [96oc][32ci][3][3] -> [ci][ky][96oc][3kx]
// wH6u: d1w [32oc][96ci][3][3] -> half2 [cp][ky][kx][32oc]   (pair = ci 2cp,2cp+1)
// wH7u: d2w [3oc][32ci][3][3]  -> half2 [cp][ky][kx][3oc]    (16 cp)
__global__ __launch_bounds__(256) void k0t(const float* __restrict__ cb,
                                           float* __restrict__ cnorm,
                                           float* __restrict__ lossacc,
                                           const float* __restrict__ e2w,
                                           float* __restrict__ wT2,
                                           const float* __restrict__ d1w,
                                           unsigned int* __restrict__ wH6u,
                                           const float* __restrict__ d2w,
                                           unsigned int* __restrict__ wH7u) {
    int g = blockIdx.x * 256 + threadIdx.x;   // 8192 threads
    if (g < 1024) {
        float s = 0.f;
#pragma unroll
        for (int d = 0; d < 25; ++d) { float v = cb[g * 25 + d]; s += v * v; }
        cnorm[g] = s;
    }
    if (g == 0) lossacc[0] = 0.f;   // ws poisoned 0xAA each call
    for (int i = g; i < 27648; i += 8192) {
        int oc = i / 288, r = i % 288, ci = r / 9, k = r % 9;
        wT2[((ci * 3 + k / 3) * 96 + oc) * 3 + (k % 3)] = e2w[i];
    }
    for (int i = g; i < 13824; i += 8192) {
        int oc = i & 31, r = i >> 5;            // r = (cp*3+ky)*3+kx
        int kx = r % 3, r2 = r / 3, ky = r2 % 3, cp = r2 / 3;
        float a = d1w[(oc * 96 + 2 * cp) * 9 + ky * 3 + kx];
        float b = d1w[(oc * 96 + 2 * cp + 1) * 9 + ky * 3 + kx];
        h2 v; v.x = (_Float16)a; v.y = (_Float16)b;
        wH6u[i] = bitsh2(v);
    }
    if (g < 432) {
        int oc = g % 3, r = g / 3;
        int kx = r % 3, r2 = r / 3, ky = r2 % 3, cp = r2 / 3;
        float a = d2w[(oc * 32 + 2 * cp) * 9 + ky * 3 + kx];
        float b = d2w[(oc * 32 + 2 * cp + 1) * 9 + ky * 3 + kx];
        h2 v; v.x = (_Float16)a; v.y = (_Float16)b;
        wH7u[g] = bitsh2(v);
    }
}

// ---------------- K1: enc1 conv3x3(3->32)+relu+pool, lane = pooled pos ----------------
__global__ __launch_bounds__(128) void k1_enc1(const float* __restrict__ x,
                                               const float* __restrict__ w,   // [32][3][9]
                                               const float* __restrict__ bias,
                                               float* __restrict__ p1,
                                               u64* __restrict__ idx1p) {
    const int img = blockIdx.x;
    const int tid = threadIdx.x;
    __shared__ __align__(16) float xs[1320];   // [3][20][22], x-padded
    __shared__ float wss[864];
    __shared__ float bss[32];
    for (int i = tid; i < 1320; i += 128) xs[i] = 0.f;
    for (int i = tid; i < 864; i += 128) wss[i] = w[i];
    if (tid < 32) bss[tid] = bias[tid];
    __syncthreads();
    for (int i = tid; i < 1200; i += 128) {
        int ci = i / 400, s = i % 400, y = s / 20, xx = s % 20;
        xs[ci * 440 + y * 22 + xx + 1] = x[img * 1200 + i];
    }
    __syncthreads();
    if (tid >= 100) return;   // only LDS reads below; no barriers
    const int r = tid / 10, c = tid % 10;
    int ry[4]; bool mv[4];
#pragma unroll
    for (int wy = 0; wy < 4; ++wy) {
        int yy = 2 * r - 1 + wy;
        mv[wy] = (yy >= 0) && (yy <= 19);
        ry[wy] = min(max(yy, 0), 19);
    }
    u64 idxbits = 0;
    for (int ocg = 0; ocg < 4; ++ocg) {
        float acc[8][4];
#pragma unroll
        for (int j = 0; j < 8; ++j) {
            float bb = bss[ocg * 8 + j];
#pragma unroll
            for (int q = 0; q < 4; ++q) acc[j][q] = bb;
        }
        for (int ci = 0; ci < 3; ++ci) {
            float win[4][4];
#pragma unroll
            for (int wy = 0; wy < 4; ++wy)
#pragma unroll
                for (int wx = 0; wx < 4; ++wx) {
                    float v = xs[ci * 440 + ry[wy] * 22 + 2 * c + wx];
                    win[wy][wx] = mv[wy] ? v : 0.f;
                }
#pragma unroll
            for (int j = 0; j < 8; ++j) {
                const float* wr = &wss[((ocg * 8 + j) * 3 + ci) * 9];
#pragma unroll
                for (int q = 0; q < 4; ++q) {
                    int dr = q >> 1, dc = q & 1;
#pragma unroll
                    for (int ky = 0; ky < 3; ++ky)
#pragma unroll
                        for (int kx = 0; kx < 3; ++kx)
                            acc[j][q] = fmaf(win[dr + ky][dc + kx], wr[ky * 3 + kx], acc[j][q]);
                }
            }
        }
#pragma unroll
        for (int j = 0; j < 8; ++j) {
            int oc = ocg * 8 + j;
            float best = -1.f; int bi = 0;
#pragma unroll
            for (int q = 0; q < 4; ++q) {            // relu then FIRST-max
                float v = fmaxf(acc[j][q], 0.f);
                if (v > best) { best = v; bi = q; }
            }
            p1[img * 3200 + oc * 100 + tid] = best;
            idxbits |= (u64)bi << (2 * oc);
        }
    }
    idx1p[img * 100 + tid] = idxbits;
}

// ---------------- K2f: enc2 conv+relu+pool FUSED with pre-VQ 1x1 (96->128) ----------------
// Phase 1: wave=24oc (12 per lane-half), lane=2x2 pooled quad. z kept in LDS.
// Phase 2: e=tid/2, half-row of 25 spatial each; weights LDS-staged, pad-33 rows.
__global__ __launch_bounds__(256) void k2f(const float* __restrict__ p1,
                                           const float* __restrict__ wT2,  // [ci][ky][96][3]
                                           const float* __restrict__ bias,
                                           const float* __restrict__ prw,  // [128][96]
                                           const float* __restrict__ prb,
                                           float* __restrict__ vqb,
                                           u8* __restrict__ idx2) {
    const int img = blockIdx.x;
    const int tid = threadIdx.x;
    __shared__ __align__(16) float up[4608];    // [32][12][12] y&x padded
    __shared__ __align__(16) float wch[6912];   // phase1: 8 ci x [3ky][96oc*3kx]; phase2: zs+wst
    for (int i = tid; i < 4608; i += 256) up[i] = 0.f;
    __syncthreads();
    for (int i = tid; i < 3200; i += 256) {
        int ci = i / 100, s = i % 100;
        up[ci * 144 + (s / 10 + 1) * 12 + (s % 10) + 1] = p1[img * 3200 + i];
    }
    const int wv = tid >> 6;             // wave 0..3 (wave-uniform)
    const int l  = tid & 63;
    const int ocsub = (l >= 25) ? 1 : 0; // 2 distinct weight addrs per wave -> free
    const int pos = l - ocsub * 25;      // 0..24 pooled pos
    const bool act = (l < 50);
    const int oc0 = wv * 24 + ocsub * 12;
    const int r = pos / 5, c = pos % 5;
    float acc[12][4];
#pragma unroll
    for (int j = 0; j < 12; ++j)
#pragma unroll
        for (int q = 0; q < 4; ++q) acc[j][q] = 0.f;
    for (int chunk = 0; chunk < 4; ++chunk) {
        __syncthreads();
        for (int i = tid; i < 6912; i += 256) wch[i] = wT2[chunk * 6912 + i];
        __syncthreads();
        if (act) {
            for (int cil = 0; cil < 8; ++cil) {
                const int base = (chunk * 8 + cil) * 144;
                float win[4][4];
#pragma unroll
                for (int wy = 0; wy < 4; ++wy) {
                    float2 a = *(const float2*)&up[base + (2 * r + wy) * 12 + 2 * c];
                    float2 b = *(const float2*)&up[base + (2 * r + wy) * 12 + 2 * c + 2];
                    win[wy][0] = a.x; win[wy][1] = a.y; win[wy][2] = b.x; win[wy][3] = b.y;
                }
#pragma unroll
                for (int ky = 0; ky < 3; ++ky) {
                    const float* wk = &wch[(cil * 3 + ky) * 288 + oc0 * 3];
                    float wreg[36];
#pragma unroll
                    for (int i4 = 0; i4 < 9; ++i4)
                        *(float4*)(wreg + 4 * i4) = *(const float4*)(wk + 4 * i4);
#pragma unroll
                    for (int j = 0; j < 12; ++j)
#pragma unroll
                        for (int q = 0; q < 4; ++q) {
                            int dr = q >> 1, dc = q & 1;
#pragma unroll
                            for (int kx = 0; kx < 3; ++kx)
                                acc[j][q] = fmaf(win[dr + ky][dc + kx], wreg[j * 3 + kx], acc[j][q]);
                        }
                }
            }
        }
    }
    // ---- pool, write idx2 + z into LDS (zs overlays wch; barrier first) ----
    float* zs = wch;              // [96][28]
    float* wst = &wch[2688];      // 128 x pad33 = 4224 floats
    __syncthreads();              // all waves done reading wch/up
    if (act) {
#pragma unroll
        for (int j = 0; j < 12; ++j) {
            int oc = oc0 + j;
            float bb = bias[oc];
            float best = -1.f; int bi = 0;
#pragma unroll
            for (int q = 0; q < 4; ++q) {            // relu BEFORE pool; FIRST max
                float v = fmaxf(acc[j][q] + bb, 0.f);
                if (v > best) { best = v; bi = q; }
            }
            zs[oc * 28 + pos] = best;
            idx2[img * 2400 + oc * 25 + pos] = (u8)bi;
        }
    }
    __syncthreads();
    // ---- phase 2: vq = prw @ z + prb (order identical to old k3a: bias, ci ascending) ----
    const int e = tid >> 1, sh = tid & 1;
    const int s0 = sh * 12, ns = sh ? 13 : 12;
    float acc2[13];
    {
        float bb = prb[e];
#pragma unroll
        for (int k = 0; k < 13; ++k) acc2[k] = bb;
    }
    for (int cc = 0; cc < 3; ++cc) {
        __syncthreads();
        for (int i = tid; i < 4096; i += 256)
            wst[(i >> 5) * 33 + (i & 31)] = prw[(i >> 5) * 96 + cc * 32 + (i & 31)];
        __syncthreads();
        for (int cil = 0; cil < 32; ++cil) {
            int ci = cc * 32 + cil;
            float wvv = wst[e * 33 + cil];         // bank (e+cil)%32 -> conflict-free
            float cz[16];
#pragma unroll
            for (int i4 = 0; i4 < 4; ++i4)
                *(float4*)(cz + 4 * i4) = *(const float4*)&zs[ci * 28 + s0 + 4 * i4];
#pragma unroll
            for (int k = 0; k < 13; ++k) acc2[k] = fmaf(wvv, cz[k], acc2[k]);
        }
    }
    float* ob = up;   // up dead after phase 1
#pragma unroll
    for (int k = 0; k < 13; ++k)
        if (k < ns) ob[e * 25 + s0 + k] = acc2[k];
    __syncthreads();
    for (int i = tid; i < 3200; i += 256) vqb[img * 3200 + i] = ob[i];
}

// ---------------- K3b: VQ distances, code-chunked, broadcast LDS reads ----------------
__global__ __launch_bounds__(256) void k3b_vq2(const float* __restrict__ vq,
                                               const float* __restrict__ cb,
                                               const float* __restrict__ cnorm,
                                               float* __restrict__ pbest,
                                               int* __restrict__ pbk) {
    const int tg = blockIdx.x >> 3;      // 0..127
    const int ch = blockIdx.x & 7;       // 0..7
    const int tid = threadIdx.x;
    const int k0 = ch * 128;
    __shared__ __align__(16) float cs[128 * 28];
    for (int i = tid; i < 128 * 28; i += 256) {
        int k = i / 28, d = i % 28;
        float v = 0.f;
        if (d < 25) v = cb[(k0 + k) * 25 + d];
        else if (d == 25) v = cnorm[k0 + k];
        cs[i] = v;
    }
    const int t0 = tg * 1024 + tid * 4;
    float f2[4][25];
#pragma unroll
    for (int t = 0; t < 4; ++t)
#pragma unroll
        for (int d = 0; d < 25; ++d)
            f2[t][d] = -2.f * vq[(t0 + t) * 25 + d];
    __syncthreads();
    float best[4] = {1e30f, 1e30f, 1e30f, 1e30f};
    int bk[4] = {0, 0, 0, 0};
    for (int k = 0; k < 128; ++k) {
        const float* crow = &cs[k * 28];
        float cc[28];
#pragma unroll
        for (int i = 0; i < 7; ++i)
            *(float4*)(cc + 4 * i) = *(const float4*)(crow + 4 * i);
        const float cn = cc[25];
        const int kg = k0 + k;
#pragma unroll
        for (int t = 0; t < 4; ++t) {
            float a = cn;
#pragma unroll
            for (int d = 0; d < 25; ++d) a = fmaf(f2[t][d], cc[d], a);
            if (a < best[t]) { best[t] = a; bk[t] = kg; }   // first-min
        }
    }
#pragma unroll
    for (int t = 0; t < 4; ++t) {
        pbest[ch * 131072 + t0 + t] = best[t];
        pbk[ch * 131072 + t0 + t] = bk[t];
    }
}

// ---------------- K3r: merge chunk partials, indices, loss ----------------
__global__ __launch_bounds__(256) void k3r_reduce(const float* __restrict__ pbest,
                                                  const int* __restrict__ pbk,
                                                  const float* __restrict__ vq,
                                                  int* __restrict__ vqidx,
                                                  float* __restrict__ lossacc) {
    const int t = blockIdx.x * 256 + threadIdx.x;
    float best = 1e30f; int bk = 0;
#pragma unroll
    for (int ch = 0; ch < 8; ++ch) {
        float s = pbest[ch * 131072 + t];
        int k = pbk[ch * 131072 + t];
        if (s < best) { best = s; bk = k; }
    }
    vqidx[t] = bk;
    float fn = 0.f;
#pragma unroll
    for (int d = 0; d < 25; ++d) { float v = vq[t * 25 + d]; fn = fmaf(v, v, fn); }
    float dloc = fn + best;
#pragma unroll
    for (int off = 32; off > 0; off >>= 1) dloc += __shfl_down(dloc, off, 64);
    __shared__ float wsum[4];
    if ((threadIdx.x & 63) == 0) wsum[threadIdx.x >> 6] = dloc;
    __syncthreads();
    if (threadIdx.x == 0)
        atomicAdd(lossacc, wsum[0] + wsum[1] + wsum[2] + wsum[3]);
}

__global__ void kf_loss(const float* __restrict__ lossacc, float* __restrict__ out) {
    out[0] = 0.25f * lossacc[0] / 3276800.0f;
}

// ---------------- K5: gather codebook, trans 1x1 (128->96) + pose head ----------------
__global__ __launch_bounds__(256) void k5_latent_pose(
    const int* __restrict__ vqidx, const float* __restrict__ cb,
    const float* __restrict__ tw, const float* __restrict__ tbb,
    const float* __restrict__ w1, const float* __restrict__ b1,
    const float* __restrict__ w2, const float* __restrict__ b2,
    float* __restrict__ latg, float* __restrict__ outkp) {
    const int img = blockIdx.x;
    const int tid = threadIdx.x;
    __shared__ int idxs[128];
    __shared__ float zr[128 * 26];
    __shared__ float lat[2400];
    __shared__ float ps[256];
    __shared__ float hs[32];
    if (tid < 128) idxs[tid] = vqidx[img * 128 + tid];
    __syncthreads();
    for (int i = tid; i < 3200; i += 256) {
        int e = i / 25, d = i % 25;
        zr[e * 26 + d] = cb[idxs[e] * 25 + d];
    }
    __syncthreads();
    const int sg = tid % 5, og = tid / 5;
    if (og < 24) {
        const int oc0 = og * 4, s0 = sg * 5;
        float acc[4][5];
#pragma unroll
        for (int j = 0; j < 4; ++j)
#pragma unroll
            for (int ss = 0; ss < 5; ++ss) acc[j][ss] = 0.f;
        for (int e = 0; e < 128; ++e) {
            float zv[5];
#pragma unroll
            for (int ss = 0; ss < 5; ++ss) zv[ss] = zr[e * 26 + s0 + ss];
#pragma unroll
            for (int j = 0; j < 4; ++j) {
                float wv = tw[e * 96 + oc0 + j];
#pragma unroll
                for (int ss = 0; ss < 5; ++ss) acc[j][ss] += wv * zv[ss];
            }
        }
#pragma unroll
        for (int j = 0; j < 4; ++j) {
            float bb = tbb[oc0 + j];
#pragma unroll
            for (int ss = 0; ss < 5; ++ss) {
                float v = acc[j][ss] + bb;
                lat[(oc0 + j) * 25 + s0 + ss] = v;
                latg[img * 2400 + (oc0 + j) * 25 + s0 + ss] = v;
            }
        }
    }
    __syncthreads();
    {
        const int seg = tid >> 5, jj = tid & 31;
        float s = 0.f;
        const int i0 = seg * 300;
        for (int i = i0; i < i0 + 300; ++i) s += lat[i] * w1[i * 32 + jj];
        ps[seg * 32 + jj] = s;
    }
    __syncthreads();
    if (tid < 32) {
        float h = b1[tid];
#pragma unroll
        for (int s2 = 0; s2 < 8; ++s2) h += ps[s2 * 32 + tid];
        hs[tid] = fmaxf(h, 0.f);
    }
    __syncthreads();
    if (tid < 36) {
        float kp = b2[tid];
#pragma unroll
        for (int m = 0; m < 32; ++m) kp += hs[m] * w2[m * 36 + tid];
        outkp[img * 36 + tid] = kp;
    }
}

// ---------------- K6: unpool(idx2)+dec1 via f16 dot2; d1 stored f16 [pos][32oc] ----------
__global__ __launch_bounds__(128) void k6_dec1(const float* __restrict__ latg,
                                               const u8* __restrict__ idx2,
                                               const unsigned int* __restrict__ wH6,
                                               const float* __restrict__ bias,
                                               unsigned short* __restrict__ d1h) {
    const int img0 = blockIdx.x * 2;
    const int tid = threadIdx.x;
    __shared__ __align__(16) unsigned int uph[13824];  // 2 img x [48cp][12][12] half2
    __shared__ unsigned int wcs[2304];                 // 8cp x [9 tap][32 oc] half2
    for (int i = tid; i < 13824; i += 128) uph[i] = 0u;
    __syncthreads();
    // quad-owner staging: full-word writes only (race-free)
    for (int g = tid; g < 2400; g += 128) {
        int m = g / 1200, r2 = g % 1200;
        int cp = r2 / 25, s = r2 % 25;
        int rr = (img0 + m) * 2400 + cp * 50 + s;
        int q0 = idx2[rr], q1 = idx2[rr + 25];
        float v0 = latg[rr], v1 = latg[rr + 25];
        unsigned int wq[4] = {0u, 0u, 0u, 0u};
        wq[q0] |= f2hbits(v0);
        wq[q1] |= f2hbits(v1) << 16;
        int pr = s / 5, pc = s % 5;
        int wb = m * 6912 + (cp * 12 + 2 * pr + 1) * 12 + 2 * pc + 1;
        uph[wb]      = wq[0];
        uph[wb + 1]  = wq[1];
        uph[wb + 12] = wq[2];
        uph[wb + 13] = wq[3];
    }
    const int m = tid >> 6;
    const int l = tid & 63;
    const int oc = l & 31, ys = l >> 5;
    float acc[50];
#pragma unroll
    for (int i = 0; i < 50; ++i) acc[i] = 0.f;
    for (int chunk = 0; chunk < 6; ++chunk) {
        __syncthreads();
        for (int i = tid; i < 2304; i += 128) wcs[i] = wH6[chunk * 2304 + i];
        __syncthreads();
        for (int cpl = 0; cpl < 8; ++cpl) {
            const int base = m * 6912 + (chunk * 8 + cpl) * 144 + ys * 60;
            unsigned int row[7][12];
#pragma unroll
            for (int k = 0; k < 7; ++k) {
                const uint4* rp = (const uint4*)&uph[base + k * 12];
                uint4 a = rp[0], b = rp[1], cc = rp[2];
                row[k][0] = a.x;  row[k][1] = a.y;  row[k][2] = a.z;  row[k][3] = a.w;
                row[k][4] = b.x;  row[k][5] = b.y;  row[k][6] = b.z;  row[k][7] = b.w;
                row[k][8] = cc.x; row[k][9] = cc.y; row[k][10] = cc.z; row[k][11] = cc.w;
            }
            h2 w9[9];
#pragma unroll
            for (int t = 0; t < 9; ++t) w9[t] = h2bits(wcs[(cpl * 9 + t) * 32 + oc]);
#pragma unroll
            for (int r = 0; r < 5; ++r)
#pragma unroll
                for (int j = 0; j < 10; ++j) {
                    float a = acc[r * 10 + j];
#pragma unroll
                    for (int ky = 0; ky < 3; ++ky)
#pragma unroll
                        for (int kx = 0; kx < 3; ++kx)
                            a = fdot2(h2bits(row[r + ky][j + kx]), w9[ky * 3 + kx], a);
                    acc[r * 10 + j] = a;
                }
        }
    }
    const float bb = bias[oc];
#pragma unroll
    for (int r = 0; r < 5; ++r)
#pragma unroll
        for (int j = 0; j < 10; ++j)
            d1h[(img0 + m) * 3200 + ((ys * 5 + r) * 10 + j) * 32 + oc] =
                (unsigned short)f2hbits(fmaxf(acc[r * 10 + j] + bb, 0.f));
}

// ---------------- K7 v2: unpool(idx1) + dec2 via f16 dot2 -> r_x ----------------
// d1 read as u32 (ci-pair half2); race-free quad staging; LDS ~30 KB.
__global__ __launch_bounds__(256) void k7_dec2(const unsigned int* __restrict__ d1w32,
                                               const u64* __restrict__ idx1p,
                                               const unsigned int* __restrict__ wH7,
                                               const float* __restrict__ bias,
                                               float* __restrict__ rx) {
    const int img = blockIdx.x;
    const int tid = threadIdx.x;
    __shared__ __align__(16) unsigned int uph[7040];   // [16cp][20][22] half2, x-padded
    __shared__ unsigned int wcs[448];                  // cp*28 + tap*3 + oc (27 used)
    for (int i = tid; i < 7040; i += 256) uph[i] = 0u;
    for (int i = tid; i < 448; i += 256) {
        int cp = i / 28, rr = i % 28;
        wcs[i] = (rr < 27) ? wH7[cp * 27 + rr] : 0u;
    }
    __syncthreads();
    for (int g = tid; g < 1600; g += 256) {
        int pos = g >> 4, cp = g & 15;
        unsigned int word = d1w32[img * 1600 + g];
        u64 bits = idx1p[img * 100 + pos];
        int q0 = (int)((bits >> (4 * cp)) & 3ull);
        int q1 = (int)((bits >> (4 * cp + 2)) & 3ull);
        unsigned int wq[4] = {0u, 0u, 0u, 0u};
        wq[q0] |= word & 0xFFFFu;
        wq[q1] |= word & 0xFFFF0000u;
        int r = pos / 10, c = pos % 10;
        int wb = cp * 440 + (2 * r) * 22 + 2 * c + 1;
        uph[wb]      = wq[0];
        uph[wb + 1]  = wq[1];
        uph[wb + 22] = wq[2];
        uph[wb + 23] = wq[3];
    }
    __syncthreads();
    if (tid >= 200) return;   // only LDS reads below
    const int y = tid / 10, xp = tid % 10, x0 = 2 * xp;
    const bool m0 = (y > 0), m2 = (y < 19);
    const int ry0 = max(y - 1, 0), ry2 = min(y + 1, 19);
    float acc[3][2] = {{0.f, 0.f}, {0.f, 0.f}, {0.f, 0.f}};
    for (int cp = 0; cp < 16; ++cp) {
        const int base = cp * 440;
        unsigned int row[3][4];
        {
            uint2 a = *(const uint2*)&uph[base + ry0 * 22 + x0];
            uint2 b = *(const uint2*)&uph[base + ry0 * 22 + x0 + 2];
            row[0][0] = m0 ? a.x : 0u; row[0][1] = m0 ? a.y : 0u;
            row[0][2] = m0 ? b.x : 0u; row[0][3] = m0 ? b.y : 0u;
            a = *(const uint2*)&uph[base + y * 22 + x0];
            b = *(const uint2*)&uph[base + y * 22 + x0 + 2];
            row[1][0] = a.x; row[1][1] = a.y; row[1][2] = b.x; row[1][3] = b.y;
            a = *(const uint2*)&uph[base + ry2 * 22 + x0];
            b = *(const uint2*)&uph[base + ry2 * 22 + x0 + 2];
            row[2][0] = m2 ? a.x : 0u; row[2][1] = m2 ? a.y : 0u;
            row[2][2] = m2 ? b.x : 0u; row[2][3] = m2 ? b.y : 0u;
        }
#pragma unroll
        for (int oc = 0; oc < 3; ++oc)
#pragma unroll
            for (int ky = 0; ky < 3; ++ky)
#pragma unroll
                for (int kx = 0; kx < 3; ++kx) {
                    h2 wk = h2bits(wcs[cp * 28 + (ky * 3 + kx) * 3 + oc]);
                    acc[oc][0] = fdot2(h2bits(row[ky][kx]),     wk, acc[oc][0]);
                    acc[oc][1] = fdot2(h2bits(row[ky][kx + 1]), wk, acc[oc][1]);
                }
    }
#pragma unroll
    for (int oc = 0; oc < 3; ++oc)
#pragma unroll
        for (int dx = 0; dx < 2; ++dx)
            rx[img * 1200 + oc * 400 + y * 20 + x0 + dx] = acc[oc][dx] + bias[oc];
}

extern "C" void kernel_launch(void* const* d_in, const int* in_sizes, int n_in,
                              void* d_out, int out_size, void* d_ws, size_t ws_size,
                              hipStream_t stream) {
    const float* x   = (const float*)d_in[0];
    const float* e1w = (const float*)d_in[1];
    const float* e1b = (const float*)d_in[2];
    const float* e2w = (const float*)d_in[3];
    const float* e2b = (const float*)d_in[4];
    const float* prw = (const float*)d_in[5];
    const float* prb = (const float*)d_in[6];
    const float* cb  = (const float*)d_in[7];
    const float* tw  = (const float*)d_in[8];
    const float* tbb = (const float*)d_in[9];
    const float* d1w = (const float*)d_in[10];
    const float* d1b = (const float*)d_in[11];
    const float* d2w = (const float*)d_in[12];
    const float* d2b = (const float*)d_in[13];
    const float* hw1 = (const float*)d_in[14];
    const float* hb1 = (const float*)d_in[15];
    const float* hw2 = (const float*)d_in[16];
    const float* hb2 = (const float*)d_in[17];
    float* out = (float*)d_out;

    float* ws      = (float*)d_ws;
    float* cnorm   = ws;                         // 1024
    float* lossacc = cnorm + 1024;               // 4
    float* wT2     = lossacc + 4;                // 27648
    unsigned int* wH6u = (unsigned int*)(wT2 + 27648);   // 13824 u32
    unsigned int* wH7u = wH6u + 13824;                   // 432 u32 (inside 27648-float slot)
    float* p1      = wT2 + 27648 + 27648;        // 3,276,800 (reused as latent after k2f)
    float* z       = p1 + 3276800;               // 2,457,600 (pbest/pbk overlay)
    float* vq      = z + 2457600;                // 3,276,800 (reused as d1h after k3r)
    int*   vqidx   = (int*)(vq + 3276800);       // 131,072
    u64*   idx1p   = (u64*)(vqidx + 131072);     // 102,400 u64
    u8*    idx2    = (u8*)(idx1p + 102400);      // 2,457,600 B
    float* latent  = p1;
    unsigned short* d1h = (unsigned short*)vq;   // 1024 x 3200 f16
    float* pbest   = z;                          // 1,048,576
    int*   pbk     = (int*)(z + 1048576);        // 1,048,576

    float* rx  = out + 1;
    float* okp = out + 1 + 1228800;

    k0t<<<32, 256, 0, stream>>>(cb, cnorm, lossacc, e2w, wT2, d1w, wH6u, d2w, wH7u);
    k1_enc1<<<1024, 128, 0, stream>>>(x, e1w, e1b, p1, idx1p);
    k2f<<<1024, 256, 0, stream>>>(p1, wT2, e2b, prw, prb, vq, idx2);
    k3b_vq2<<<1024, 256, 0, stream>>>(vq, cb, cnorm, pbest, pbk);
    k3r_reduce<<<512, 256, 0, stream>>>(pbest, pbk, vq, vqidx, lossacc);
    kf_loss<<<1, 1, 0, stream>>>(lossacc, out);
    k5_latent_pose<<<1024, 256, 0, stream>>>(vqidx, cb, tw, tbb, hw1, hb1, hw2, hb2,
                                             latent, okp);
    k6_dec1<<<512, 128, 0, stream>>>(latent, idx2, wH6u, d1b, d1h);
    k7_dec2<<<1024, 256, 0, stream>>>((const unsigned int*)d1h, idx1p, wH7u, d2b, rx);
}